// Round 15
// baseline (543.279 us; speedup 1.0000x reference)
//
#include <hip/hip_runtime.h>
#include <hip/hip_bf16.h>

#define D_IN 256
#define D_OUT 64

#define BSH 7                 // 128 nodes per bucket
#define BNODES 128
#define BNB 391               // ceil(50000 / 128)
#define EPB 4096              // edges per bin block
#define ENT_CAP 2560          // staged entries per bucket (mean 2046, ~11 sigma)

typedef __bf16 bf16x8 __attribute__((ext_vector_type(8)));
typedef float f32x4 __attribute__((ext_vector_type(4)));

// ---------------------------------------------------------------------------
// P0: transpose+split weight: w[256][64] fp32 -> wt_hi/wt_lo[64][256] bf16.
// ---------------------------------------------------------------------------
__global__ __launch_bounds__(256) void prep_w_kernel(
    const float* __restrict__ w, __bf16* __restrict__ wt_hi,
    __bf16* __restrict__ wt_lo) {
    int i = blockIdx.x * 256 + threadIdx.x;   // [0, 16384)
    int c = i >> 8;                            // col 0..63
    int k = i & 255;                           // k   0..255
    float v = w[k * D_OUT + c];
    __bf16 h = (__bf16)v;
    wt_hi[i] = h;
    wt_lo[i] = (__bf16)(v - (float)h);
}

// ---------------------------------------------------------------------------
// K1: xw = x @ W via 3-MFMA split-bf16 (measured good; unchanged).
// ---------------------------------------------------------------------------
__global__ __launch_bounds__(256) void gemm_mfma_kernel(
    const float* __restrict__ x, const __bf16* __restrict__ wt_hi,
    const __bf16* __restrict__ wt_lo, float* __restrict__ xw, int n_rows) {
    int lane = threadIdx.x & 63;
    int wid  = threadIdx.x >> 6;
    int row0 = blockIdx.x * 64 + wid * 16;

    int fr = lane & 15;
    int ko = (lane >> 4) * 8;

    int arow = row0 + fr;
    if (arow >= n_rows) arow = n_rows - 1;
    const float* xr = x + (size_t)arow * D_IN + ko;

    f32x4 acc[4] = {{0.f, 0.f, 0.f, 0.f}, {0.f, 0.f, 0.f, 0.f},
                    {0.f, 0.f, 0.f, 0.f}, {0.f, 0.f, 0.f, 0.f}};

#pragma unroll
    for (int ks = 0; ks < 8; ++ks) {
        float4 a0 = *(const float4*)(xr + ks * 32);
        float4 a1 = *(const float4*)(xr + ks * 32 + 4);
        float av[8] = {a0.x, a0.y, a0.z, a0.w, a1.x, a1.y, a1.z, a1.w};
        bf16x8 ah, al;
#pragma unroll
        for (int j = 0; j < 8; ++j) {
            __bf16 h = (__bf16)av[j];
            ah[j] = h;
            al[j] = (__bf16)(av[j] - (float)h);
        }
#pragma unroll
        for (int ct = 0; ct < 4; ++ct) {
            const __bf16* bp = wt_hi + (size_t)(ct * 16 + fr) * D_IN + ks * 32 + ko;
            const __bf16* lp = wt_lo + (size_t)(ct * 16 + fr) * D_IN + ks * 32 + ko;
            bf16x8 bh = *(const bf16x8*)bp;
            bf16x8 bl = *(const bf16x8*)lp;
            acc[ct] = __builtin_amdgcn_mfma_f32_16x16x32_bf16(ah, bh, acc[ct], 0, 0, 0);
            acc[ct] = __builtin_amdgcn_mfma_f32_16x16x32_bf16(al, bh, acc[ct], 0, 0, 0);
            acc[ct] = __builtin_amdgcn_mfma_f32_16x16x32_bf16(ah, bl, acc[ct], 0, 0, 0);
        }
    }

    int crow0 = row0 + (lane >> 4) * 4;
#pragma unroll
    for (int ct = 0; ct < 4; ++ct) {
        int col = ct * 16 + fr;
#pragma unroll
        for (int j = 0; j < 4; ++j) {
            int row = crow0 + j;
            if (row < n_rows) xw[(size_t)row * D_OUT + col] = acc[ct][j];
        }
    }
}

// ---------------------------------------------------------------------------
// zero bucket histogram (391 ints)
// ---------------------------------------------------------------------------
__global__ __launch_bounds__(512) void zero_small_kernel(int* __restrict__ bhist) {
    int t = threadIdx.x;
    if (t < BNB) bhist[t] = 0;
}

// ---------------------------------------------------------------------------
// bucket histogram, LDS-aggregated (few global atomics on hot lines)
// ---------------------------------------------------------------------------
__global__ __launch_bounds__(256) void bhist_kernel(
    const int* __restrict__ edst, int* __restrict__ bhist, int n_edges) {
    __shared__ int lh[BNB];
    int t = threadIdx.x;
    for (int s = t; s < BNB; s += 256) lh[s] = 0;
    __syncthreads();
    int base = blockIdx.x * EPB;
    int nv = n_edges - base; if (nv > EPB) nv = EPB;
#pragma unroll
    for (int j = 0; j < 16; ++j) {
        int idx = j * 256 + t;
        if (idx < nv) atomicAdd(&lh[edst[base + idx] >> BSH], 1);
    }
    __syncthreads();
    for (int s = t; s < BNB; s += 256)
        if (lh[s]) atomicAdd(&bhist[s], lh[s]);
}

// ---------------------------------------------------------------------------
// exclusive scan of bhist -> gstart (bucket region bases) and gcur copy
// ---------------------------------------------------------------------------
__global__ __launch_bounds__(512) void bscan_kernel(
    const int* __restrict__ bhist, int* __restrict__ gstart,
    int* __restrict__ gcur) {
    __shared__ int lds[512];
    int t = threadIdx.x;
    lds[t] = (t < BNB) ? bhist[t] : 0;
    __syncthreads();
    for (int d = 1; d < 512; d <<= 1) {        // Hillis-Steele inclusive
        int v = (t >= d) ? lds[t - d] : 0;
        __syncthreads();
        lds[t] += v;
        __syncthreads();
    }
    if (t < BNB) {
        int ex = (t == 0) ? 0 : lds[t - 1];
        gstart[t] = ex;
        gcur[t] = ex;
    }
}

// ---------------------------------------------------------------------------
// bin1: per-block in-LDS counting sort by bucket, then COALESCED run writes
// (full 64B lines -> kills the 8x write amplification the old scatter had).
// Entry pack: x = src | (dst&127)<<17 ; y = bitcast(val).
// ---------------------------------------------------------------------------
__global__ __launch_bounds__(256) void bin1_kernel(
    const int* __restrict__ esrc, const int* __restrict__ edst,
    const float* __restrict__ eval, int* __restrict__ gcur,
    int2* __restrict__ binned, int n_edges) {
    __shared__ int2 spair[EPB];
    __shared__ unsigned short sbkt[EPB];
    __shared__ int cnt[BNB];
    __shared__ int bstart[BNB];
    __shared__ int gbase[BNB];
    __shared__ int part[256];

    int t = threadIdx.x;
    int base = blockIdx.x * EPB;
    int nv = n_edges - base; if (nv > EPB) nv = EPB;

    for (int s = t; s < BNB; s += 256) cnt[s] = 0;
    __syncthreads();

    int2 pr[16];
    int rk[16];
#pragma unroll
    for (int j = 0; j < 16; ++j) {
        int idx = j * 256 + t;
        if (idx < nv) {
            int e = base + idx;
            int d = edst[e];
            int b = d >> BSH;
            pr[j].x = esrc[e] | ((d & (BNODES - 1)) << 17);
            pr[j].y = __float_as_int(eval[e]);
            int r = atomicAdd(&cnt[b], 1);
            rk[j] = r | (b << 13);             // r<4096 (13b), b<391 (9b)
        }
    }
    __syncthreads();

    // exclusive scan of cnt (2 slots/thread covers 512 >= BNB)
    int s0 = (2 * t < BNB) ? cnt[2 * t] : 0;
    int s1 = (2 * t + 1 < BNB) ? cnt[2 * t + 1] : 0;
    part[t] = s0 + s1;
    __syncthreads();
    for (int d = 1; d < 256; d <<= 1) {
        int v = (t >= d) ? part[t - d] : 0;
        __syncthreads();
        part[t] += v;
        __syncthreads();
    }
    int pbase = (t == 0) ? 0 : part[t - 1];
    if (2 * t < BNB) bstart[2 * t] = pbase;
    if (2 * t + 1 < BNB) bstart[2 * t + 1] = pbase + s0;
    __syncthreads();

    // scatter into LDS bucket-sorted order
#pragma unroll
    for (int j = 0; j < 16; ++j) {
        int idx = j * 256 + t;
        if (idx < nv) {
            int b = rk[j] >> 13;
            int r = rk[j] & 8191;
            int pos = bstart[b] + r;
            spair[pos] = pr[j];
            sbkt[pos] = (unsigned short)b;
        }
    }
    __syncthreads();

    // reserve global ranges per bucket
    for (int s = t; s < BNB; s += 256)
        if (cnt[s] > 0) gbase[s] = atomicAdd(&gcur[s], cnt[s]);
    __syncthreads();

    // coalesced write-out: consecutive idx -> mostly consecutive global addr
    for (int idx = t; idx < nv; idx += 256) {
        int b = sbkt[idx];
        binned[gbase[b] + (idx - bstart[b])] = spair[idx];
    }
}

// ---------------------------------------------------------------------------
// bucket_gather: one block per 128-node bucket. LDS f32 tile accumulates
// val*xw[src] via LDS atomics (lane=col -> 2-way bank alias, free).
// bias init + ReLU fused. 4-deep load pipeline per wave for latency hiding.
// ---------------------------------------------------------------------------
__global__ __launch_bounds__(256) void bucket_gather_kernel(
    const float* __restrict__ xw, const int2* __restrict__ binned,
    const int* __restrict__ gstart, const int* __restrict__ bhist,
    const float* __restrict__ bias, float* __restrict__ out, int n_nodes) {
    __shared__ float tile[BNODES * D_OUT];     // 32 KB
    __shared__ int2 ent[ENT_CAP];              // 20 KB
    int t = threadIdx.x;
    int b = blockIdx.x;
    int node0 = b << BSH;

    for (int i = t; i < BNODES * D_OUT; i += 256) tile[i] = bias[i & 63];

    int start = gstart[b];
    int cnt = bhist[b];
    for (int i = t; i < cnt && i < ENT_CAP; i += 256) ent[i] = binned[start + i];
    __syncthreads();

    int wid = t >> 6, lane = t & 63;
    for (int i0 = wid; i0 < cnt; i0 += 16) {
        int2 p[4];
        float m[4];
#pragma unroll
        for (int j = 0; j < 4; ++j) {
            int i = i0 + j * 4;
            if (i < cnt) {
                p[j] = (i < ENT_CAP) ? ent[i] : binned[start + i];
                m[j] = xw[(size_t)(p[j].x & 0x1FFFF) * D_OUT + lane];
            }
        }
#pragma unroll
        for (int j = 0; j < 4; ++j) {
            int i = i0 + j * 4;
            if (i < cnt)
                atomicAdd(&tile[((p[j].x >> 17) & (BNODES - 1)) * D_OUT + lane],
                          __int_as_float(p[j].y) * m[j]);
        }
    }
    __syncthreads();

    for (int i = t; i < BNODES * D_OUT; i += 256) {
        int node = node0 + (i >> 6);
        if (node < n_nodes)
            out[(size_t)node * D_OUT + (i & 63)] = fmaxf(tile[i], 0.f);
    }
}

extern "C" void kernel_launch(void* const* d_in, const int* in_sizes, int n_in,
                              void* d_out, int out_size, void* d_ws, size_t ws_size,
                              hipStream_t stream) {
    const float* x    = (const float*)d_in[0];
    const int*   esrc = (const int*)d_in[1];
    const int*   edst = (const int*)d_in[2];
    const float* eval = (const float*)d_in[3];
    const float* w    = (const float*)d_in[4];
    const float* bias = (const float*)d_in[5];
    float*       out  = (float*)d_out;

    int n_nodes = in_sizes[0] / D_IN;
    int n_edges = in_sizes[1];

    // workspace layout (~19.3 MB)
    char* p = (char*)d_ws;
    float* xw = (float*)p;            p += (size_t)n_nodes * D_OUT * 4;
    __bf16* wt_hi = (__bf16*)p;       p += (size_t)D_IN * D_OUT * 2;
    __bf16* wt_lo = (__bf16*)p;       p += (size_t)D_IN * D_OUT * 2;
    int* bhist = (int*)p;             p += (size_t)BNB * 4;
    int* gstart = (int*)p;            p += (size_t)BNB * 4;
    int* gcur = (int*)p;              p += (size_t)BNB * 4;
    p = (char*)(((uintptr_t)p + 15) & ~(uintptr_t)15);
    int2* binned = (int2*)p;

    int nbin = (n_edges + EPB - 1) / EPB;      // 196

    prep_w_kernel<<<(D_IN * D_OUT + 255) / 256, 256, 0, stream>>>(w, wt_hi, wt_lo);
    zero_small_kernel<<<1, 512, 0, stream>>>(bhist);
    bhist_kernel<<<nbin, 256, 0, stream>>>(edst, bhist, n_edges);
    bscan_kernel<<<1, 512, 0, stream>>>(bhist, gstart, gcur);
    bin1_kernel<<<nbin, 256, 0, stream>>>(esrc, edst, eval, gcur, binned, n_edges);
    gemm_mfma_kernel<<<(n_nodes + 63) / 64, 256, 0, stream>>>(x, wt_hi, wt_lo,
                                                              xw, n_nodes);
    bucket_gather_kernel<<<BNB, 256, 0, stream>>>(xw, binned, gstart, bhist,
                                                  bias, out, n_nodes);
}